// Round 12
// baseline (97.885 us; speedup 1.0000x reference)
//
#include <hip/hip_runtime.h>
#include <hip/hip_bf16.h>

#define TT 24
#define NN 1000
#define DD 64
#define TCH 12                 // timesteps per wave (2 chunks)
#define NCH (TT / TCH)         // 2
#define NT  63                 // ceil(1000/16) node tiles

typedef short bf16x8 __attribute__((ext_vector_type(8)));
typedef float f32x4  __attribute__((ext_vector_type(4)));

__device__ __forceinline__ short f2bf(float f) {
    __hip_bfloat16 h = __float2bfloat16(f);
    return *reinterpret_cast<short*>(&h);
}

// r12 = r11 with ONE change: plain stores instead of __builtin_nontemporal_store.
// Rationale: vmcnt is in-order and counts stores; nt stores may only retire at
// HBM (~600-900cy) vs L2 ack (~100-200cy), so every prefetch-load wait drags a
// store round-trip onto the critical path. Also WRITE_SIZE showed +10-18%
// inflation (211-227MB vs 192MB ideal) under nt.
__global__ __launch_bounds__(64, 2)
void stgcn_d2c(const float* __restrict__ x,
               const float* __restrict__ w1, const float* __restrict__ b1,
               const float* __restrict__ w2, const float* __restrict__ b2,
               const float* __restrict__ gamma, const float* __restrict__ beta,
               float* __restrict__ out)
{
    const int l   = threadIdx.x & 63;
    const int lr  = l & 15;        // node within tile (C col); frag row
    const int lc  = l >> 4;        // 0..3

    const int w  = __builtin_amdgcn_readfirstlane(blockIdx.x);
    const int nt = w % NT;
    const int tc = (w / NT) % NCH;
    const int b  = w / (NT * NCH);
    const int t0 = tc * TCH;
    const int n0 = nt * 16;

    // ---- single per-lane offset: row lr, word col lc*4 (+16nf immediates)
    const int rowA = min(n0 + lr, NN - 1);
    const int offQ = rowA * DD + lc * 4;

    const size_t ts = (size_t)NN * DD;
    const float* px = x   + (size_t)(b*TT + t0) * ts;   // SGPR slab base
    float*       po = out + (size_t)(b*TT + t0) * ts;

    // ---- issue t0 and t0+1 tile loads ASAP
    f32x4 qA0 = *(const f32x4*)(px + offQ);
    f32x4 qA1 = *(const f32x4*)(px + offQ + 16);
    f32x4 qA2 = *(const f32x4*)(px + offQ + 32);
    f32x4 qA3 = *(const f32x4*)(px + offQ + 48);
    f32x4 qB0 = *(const f32x4*)(px + ts + offQ);
    f32x4 qB1 = *(const f32x4*)(px + ts + offQ + 16);
    f32x4 qB2 = *(const f32x4*)(px + ts + offQ + 32);
    f32x4 qB3 = *(const f32x4*)(px + ts + offQ + 48);
    f32x4 qC0, qC1, qC2, qC3;

    // ---- x_{t0-1} as bf16 frags; zero-pad at t0==0
    bf16x8 XA[2], XB[2];
    if (t0 > 0) {
        const float* pm = px - ts;
        f32x4 m0 = *(const f32x4*)(pm + offQ);
        f32x4 m1 = *(const f32x4*)(pm + offQ + 16);
        f32x4 m2 = *(const f32x4*)(pm + offQ + 32);
        f32x4 m3 = *(const f32x4*)(pm + offQ + 48);
#pragma unroll
        for (int j = 0; j < 4; ++j) {
            XA[0][j]     = f2bf(m0[j]);
            XA[0][4 + j] = f2bf(m1[j]);
            XA[1][j]     = f2bf(m2[j]);
            XA[1][4 + j] = f2bf(m3[j]);
        }
    } else {
        XA[0] = 0; XA[1] = 0;
    }

    // ---- W fragments (A-operand), k-permuted: slot j <- col lc*4+(j&3)+16*(j>>2)+32ks
    bf16x8 W1f[4][2], W2f[4][2];
#pragma unroll
    for (int nf = 0; nf < 4; ++nf) {
#pragma unroll
        for (int ks = 0; ks < 2; ++ks) {
            const float* p1 = &w1[(size_t)(lr + 16*nf) * DD + lc*4 + 32*ks];
            const float* p2 = &w2[(size_t)(lr + 16*nf) * DD + lc*4 + 32*ks];
            f32x4 u0 = *(const f32x4*)p1, u1 = *(const f32x4*)(p1 + 16);
            f32x4 v0 = *(const f32x4*)p2, v1 = *(const f32x4*)(p2 + 16);
#pragma unroll
            for (int j = 0; j < 4; ++j) {
                W1f[nf][ks][j]     = f2bf(0.5f * u0[j]);
                W1f[nf][ks][4 + j] = f2bf(0.5f * u1[j]);
                W2f[nf][ks][j]     = f2bf(0.5f * v0[j]);
                W2f[nf][ks][4 + j] = f2bf(0.5f * v1[j]);
            }
        }
    }
    // ---- epilogue params at d = 16*nf + lc*4 + i
    f32x4 bia1[4], bia2[4], gmm[4], btt[4];
#pragma unroll
    for (int nf = 0; nf < 4; ++nf) {
        const int d0 = 16*nf + lc*4;
        bia1[nf] = *(const f32x4*)&b1[d0];
        bia2[nf] = *(const f32x4*)&b2[d0];
        gmm[nf]  = *(const f32x4*)&gamma[d0];
        btt[nf]  = *(const f32x4*)&beta[d0];
    }

    auto step = [&](int t,
                    f32x4& q0, f32x4& q1, f32x4& q2, f32x4& q3,   // arrived tile (t)
                    f32x4& p0, f32x4& p1, f32x4& p2, f32x4& p3,   // prefetch dest (t+2)
                    bf16x8 (&Xi)[2], bf16x8 (&Xo)[2]) {
        // depth-2 prefetch (clamped at chunk end; dup loads harmless)
        const float* pn = px + (size_t)min(t + 2, TCH - 1) * ts;
        p0 = *(const f32x4*)(pn + offQ);
        p1 = *(const f32x4*)(pn + offQ + 16);
        p2 = *(const f32x4*)(pn + offQ + 32);
        p3 = *(const f32x4*)(pn + offQ + 48);

        // pass 1: prev-frame MFMAs, bias as C-init (register inputs, no waits)
        f32x4 C1[4], C2[4];
#pragma unroll
        for (int nf = 0; nf < 4; ++nf) {
            C1[nf] = __builtin_amdgcn_mfma_f32_16x16x32_bf16(W1f[nf][0], Xi[0], bia1[nf], 0, 0, 0);
            C1[nf] = __builtin_amdgcn_mfma_f32_16x16x32_bf16(W1f[nf][1], Xi[1], C1[nf],   0, 0, 0);
            C2[nf] = __builtin_amdgcn_mfma_f32_16x16x32_bf16(W2f[nf][0], Xi[0], bia2[nf], 0, 0, 0);
            C2[nf] = __builtin_amdgcn_mfma_f32_16x16x32_bf16(W2f[nf][1], Xi[1], C2[nf],   0, 0, 0);
        }

        // arrived tile -> bf16 frags for this step (and next step's prev)
#pragma unroll
        for (int j = 0; j < 4; ++j) {
            Xo[0][j]     = f2bf(q0[j]);
            Xo[0][4 + j] = f2bf(q1[j]);
            Xo[1][j]     = f2bf(q2[j]);
            Xo[1][4 + j] = f2bf(q3[j]);
        }
        // pass 2: current-frame MFMAs
#pragma unroll
        for (int nf = 0; nf < 4; ++nf) {
            C1[nf] = __builtin_amdgcn_mfma_f32_16x16x32_bf16(W1f[nf][0], Xo[0], C1[nf], 0, 0, 0);
            C1[nf] = __builtin_amdgcn_mfma_f32_16x16x32_bf16(W1f[nf][1], Xo[1], C1[nf], 0, 0, 0);
            C2[nf] = __builtin_amdgcn_mfma_f32_16x16x32_bf16(W2f[nf][0], Xo[0], C2[nf], 0, 0, 0);
            C2[nf] = __builtin_amdgcn_mfma_f32_16x16x32_bf16(W2f[nf][1], Xo[1], C2[nf], 0, 0, 0);
        }

        // epilogue: residual IS the q regs (k-permutation payoff)
        float sa = 0.f, sb = 0.f, s2a = 0.f, s2b = 0.f;
        const f32x4* xr[4] = { &q0, &q1, &q2, &q3 };
#pragma unroll
        for (int nf = 0; nf < 4; ++nf) {
#pragma unroll
            for (int i = 0; i < 4; ++i) {
                float h1 = C1[nf][i];          // bias already in C
                float h2 = C2[nf][i];
                float pg = h1 * h2;
                float oo = (pg > 0.f ? pg : 0.f) + h1 + (*xr[nf])[i];
                C1[nf][i] = oo;                // reuse C1 as o
                if (nf & 1) { sb += oo; s2b = fmaf(oo, oo, s2b); }
                else        { sa += oo; s2a = fmaf(oo, oo, s2a); }
            }
        }
        float s  = sa + sb;
        float s2 = s2a + s2b;
        s  += __shfl_xor(s,  16, 64);  s  += __shfl_xor(s,  32, 64);
        s2 += __shfl_xor(s2, 16, 64);  s2 += __shfl_xor(s2, 32, 64);
        float mu = s * (1.f/64.f);
        float va = fmaf(s2, 1.f/64.f, -mu*mu);
        float rs = rsqrtf(va + 1e-5f);

        if (n0 + lr < NN) {               // clamped duplicate lanes don't store
            float* pot = po + (size_t)t * ts;
#pragma unroll
            for (int nf = 0; nf < 4; ++nf) {
                f32x4 v;
#pragma unroll
                for (int i = 0; i < 4; ++i)
                    v[i] = fmaf((C1[nf][i] - mu) * rs, gmm[nf][i], btt[nf][i]);
                *(f32x4*)(pot + offQ + 16*nf) = v;   // plain store: fast L2 ack
            }
        }
    };

    // q rotation period 3, X parity period 2 -> unroll 6 (TCH = 12 = 2x6)
#pragma unroll 1
    for (int tb = 0; tb < TCH; tb += 6) {
        step(tb + 0, qA0,qA1,qA2,qA3,  qC0,qC1,qC2,qC3,  XA, XB);
        step(tb + 1, qB0,qB1,qB2,qB3,  qA0,qA1,qA2,qA3,  XB, XA);
        step(tb + 2, qC0,qC1,qC2,qC3,  qB0,qB1,qB2,qB3,  XA, XB);
        step(tb + 3, qA0,qA1,qA2,qA3,  qC0,qC1,qC2,qC3,  XB, XA);
        step(tb + 4, qB0,qB1,qB2,qB3,  qA0,qA1,qA2,qA3,  XA, XB);
        step(tb + 5, qC0,qC1,qC2,qC3,  qB0,qB1,qB2,qB3,  XB, XA);
    }
}

extern "C" void kernel_launch(void* const* d_in, const int* in_sizes, int n_in,
                              void* d_out, int out_size, void* d_ws, size_t ws_size,
                              hipStream_t stream) {
    const float* x     = (const float*)d_in[0];
    // d_in[1] = adj — dead in the reference (overwritten by tiled identity)
    const float* w1    = (const float*)d_in[2];
    const float* b1    = (const float*)d_in[3];
    const float* w2    = (const float*)d_in[4];
    const float* b2    = (const float*)d_in[5];
    const float* gamma = (const float*)d_in[6];
    const float* beta  = (const float*)d_in[7];
    float* out = (float*)d_out;

    dim3 grid(32 * NT * NCH);   // 4032 one-wave blocks
    dim3 block(64);
    hipLaunchKernelGGL(stgcn_d2c, grid, block, 0, stream,
                       x, w1, b1, w2, b2, gamma, beta, out);
}

// Round 13
// 89.124 us; speedup vs baseline: 1.0983x; 1.0983x over previous
//
#include <hip/hip_runtime.h>
#include <hip/hip_bf16.h>

#define TT 24
#define NN 1000
#define DD 64
#define TCH 12                 // timesteps per wave (2 chunks)
#define NCH (TT / TCH)         // 2
#define NT  63                 // ceil(1000/16) node tiles

typedef short bf16x8 __attribute__((ext_vector_type(8)));
typedef short bf16x4 __attribute__((ext_vector_type(4)));
typedef float f32x4  __attribute__((ext_vector_type(4)));

__device__ __forceinline__ short f2bf(float f) {
    __hip_bfloat16 h = __float2bfloat16(f);
    return *reinterpret_cast<short*>(&h);
}
__device__ __forceinline__ float bf2f(short s) {
    union { unsigned u; float f; } c;
    c.u = ((unsigned)(unsigned short)s) << 16;
    return c.f;
}

// r13 = r11 (best, nt stores) + depth-3 prefetch (4 rotating q-buffer sets,
// issue-to-use ~3 steps ≈ 900cy, covering HBM-miss latency) paid for by
// packing gamma/beta as bf16x4 (saves 16 VGPRs; unpack = 1 shift each in the
// epilogue). Keeps: k-permuted frags (residual lives in q regs), bias as MFMA
// C-init, SGPR slab bases, nontemporal stores (r12 A/B: plain stores regress
// the replay bench via L2 writeback contention).
__global__ __launch_bounds__(64, 2)
void stgcn_d3(const float* __restrict__ x,
              const float* __restrict__ w1, const float* __restrict__ b1,
              const float* __restrict__ w2, const float* __restrict__ b2,
              const float* __restrict__ gamma, const float* __restrict__ beta,
              float* __restrict__ out)
{
    const int l   = threadIdx.x & 63;
    const int lr  = l & 15;        // node within tile (C col); frag row
    const int lc  = l >> 4;        // 0..3

    const int w  = __builtin_amdgcn_readfirstlane(blockIdx.x);
    const int nt = w % NT;
    const int tc = (w / NT) % NCH;
    const int b  = w / (NT * NCH);
    const int t0 = tc * TCH;
    const int n0 = nt * 16;

    // ---- single per-lane offset: row lr, word col lc*4 (+16nf immediates)
    const int rowA = min(n0 + lr, NN - 1);
    const int offQ = rowA * DD + lc * 4;

    const size_t ts = (size_t)NN * DD;
    const float* px = x   + (size_t)(b*TT + t0) * ts;   // SGPR slab base
    float*       po = out + (size_t)(b*TT + t0) * ts;

    // ---- issue t0, t0+1, t0+2 tile loads ASAP (depth-3 pipeline fill)
    f32x4 qA0 = *(const f32x4*)(px + offQ);
    f32x4 qA1 = *(const f32x4*)(px + offQ + 16);
    f32x4 qA2 = *(const f32x4*)(px + offQ + 32);
    f32x4 qA3 = *(const f32x4*)(px + offQ + 48);
    f32x4 qB0 = *(const f32x4*)(px + ts + offQ);
    f32x4 qB1 = *(const f32x4*)(px + ts + offQ + 16);
    f32x4 qB2 = *(const f32x4*)(px + ts + offQ + 32);
    f32x4 qB3 = *(const f32x4*)(px + ts + offQ + 48);
    f32x4 qC0 = *(const f32x4*)(px + 2*ts + offQ);
    f32x4 qC1 = *(const f32x4*)(px + 2*ts + offQ + 16);
    f32x4 qC2 = *(const f32x4*)(px + 2*ts + offQ + 32);
    f32x4 qC3 = *(const f32x4*)(px + 2*ts + offQ + 48);
    f32x4 qD0, qD1, qD2, qD3;

    // ---- x_{t0-1} as bf16 frags; zero-pad at t0==0
    bf16x8 XA[2], XB[2];
    if (t0 > 0) {
        const float* pm = px - ts;
        f32x4 m0 = *(const f32x4*)(pm + offQ);
        f32x4 m1 = *(const f32x4*)(pm + offQ + 16);
        f32x4 m2 = *(const f32x4*)(pm + offQ + 32);
        f32x4 m3 = *(const f32x4*)(pm + offQ + 48);
#pragma unroll
        for (int j = 0; j < 4; ++j) {
            XA[0][j]     = f2bf(m0[j]);
            XA[0][4 + j] = f2bf(m1[j]);
            XA[1][j]     = f2bf(m2[j]);
            XA[1][4 + j] = f2bf(m3[j]);
        }
    } else {
        XA[0] = 0; XA[1] = 0;
    }

    // ---- W fragments (A-operand), k-permuted: slot j <- col lc*4+(j&3)+16*(j>>2)+32ks
    bf16x8 W1f[4][2], W2f[4][2];
#pragma unroll
    for (int nf = 0; nf < 4; ++nf) {
#pragma unroll
        for (int ks = 0; ks < 2; ++ks) {
            const float* p1 = &w1[(size_t)(lr + 16*nf) * DD + lc*4 + 32*ks];
            const float* p2 = &w2[(size_t)(lr + 16*nf) * DD + lc*4 + 32*ks];
            f32x4 u0 = *(const f32x4*)p1, u1 = *(const f32x4*)(p1 + 16);
            f32x4 v0 = *(const f32x4*)p2, v1 = *(const f32x4*)(p2 + 16);
#pragma unroll
            for (int j = 0; j < 4; ++j) {
                W1f[nf][ks][j]     = f2bf(0.5f * u0[j]);
                W1f[nf][ks][4 + j] = f2bf(0.5f * u1[j]);
                W2f[nf][ks][j]     = f2bf(0.5f * v0[j]);
                W2f[nf][ks][4 + j] = f2bf(0.5f * v1[j]);
            }
        }
    }
    // ---- epilogue params at d = 16*nf + lc*4 + i
    //      bias stays f32 (MFMA C-init); gamma/beta packed bf16 (saves 16 VGPR)
    f32x4 bia1[4], bia2[4];
    bf16x4 gpk[4], bpk[4];
#pragma unroll
    for (int nf = 0; nf < 4; ++nf) {
        const int d0 = 16*nf + lc*4;
        bia1[nf] = *(const f32x4*)&b1[d0];
        bia2[nf] = *(const f32x4*)&b2[d0];
        f32x4 g = *(const f32x4*)&gamma[d0];
        f32x4 be = *(const f32x4*)&beta[d0];
#pragma unroll
        for (int i = 0; i < 4; ++i) { gpk[nf][i] = f2bf(g[i]); bpk[nf][i] = f2bf(be[i]); }
    }

    auto step = [&](int t,
                    f32x4& q0, f32x4& q1, f32x4& q2, f32x4& q3,   // arrived tile (t)
                    f32x4& p0, f32x4& p1, f32x4& p2, f32x4& p3,   // prefetch dest (t+3)
                    bf16x8 (&Xi)[2], bf16x8 (&Xo)[2]) {
        // depth-3 prefetch (clamped at chunk end; dup loads harmless)
        const float* pn = px + (size_t)min(t + 3, TCH - 1) * ts;
        p0 = *(const f32x4*)(pn + offQ);
        p1 = *(const f32x4*)(pn + offQ + 16);
        p2 = *(const f32x4*)(pn + offQ + 32);
        p3 = *(const f32x4*)(pn + offQ + 48);

        // pass 1: prev-frame MFMAs, bias as C-init (register inputs, no waits)
        f32x4 C1[4], C2[4];
#pragma unroll
        for (int nf = 0; nf < 4; ++nf) {
            C1[nf] = __builtin_amdgcn_mfma_f32_16x16x32_bf16(W1f[nf][0], Xi[0], bia1[nf], 0, 0, 0);
            C1[nf] = __builtin_amdgcn_mfma_f32_16x16x32_bf16(W1f[nf][1], Xi[1], C1[nf],   0, 0, 0);
            C2[nf] = __builtin_amdgcn_mfma_f32_16x16x32_bf16(W2f[nf][0], Xi[0], bia2[nf], 0, 0, 0);
            C2[nf] = __builtin_amdgcn_mfma_f32_16x16x32_bf16(W2f[nf][1], Xi[1], C2[nf],   0, 0, 0);
        }

        // arrived tile -> bf16 frags for this step (and next step's prev)
#pragma unroll
        for (int j = 0; j < 4; ++j) {
            Xo[0][j]     = f2bf(q0[j]);
            Xo[0][4 + j] = f2bf(q1[j]);
            Xo[1][j]     = f2bf(q2[j]);
            Xo[1][4 + j] = f2bf(q3[j]);
        }
        // pass 2: current-frame MFMAs
#pragma unroll
        for (int nf = 0; nf < 4; ++nf) {
            C1[nf] = __builtin_amdgcn_mfma_f32_16x16x32_bf16(W1f[nf][0], Xo[0], C1[nf], 0, 0, 0);
            C1[nf] = __builtin_amdgcn_mfma_f32_16x16x32_bf16(W1f[nf][1], Xo[1], C1[nf], 0, 0, 0);
            C2[nf] = __builtin_amdgcn_mfma_f32_16x16x32_bf16(W2f[nf][0], Xo[0], C2[nf], 0, 0, 0);
            C2[nf] = __builtin_amdgcn_mfma_f32_16x16x32_bf16(W2f[nf][1], Xo[1], C2[nf], 0, 0, 0);
        }

        // epilogue: residual IS the q regs (k-permutation payoff)
        float sa = 0.f, sb = 0.f, s2a = 0.f, s2b = 0.f;
        const f32x4* xr[4] = { &q0, &q1, &q2, &q3 };
#pragma unroll
        for (int nf = 0; nf < 4; ++nf) {
#pragma unroll
            for (int i = 0; i < 4; ++i) {
                float h1 = C1[nf][i];          // bias already in C
                float h2 = C2[nf][i];
                float pg = h1 * h2;
                float oo = (pg > 0.f ? pg : 0.f) + h1 + (*xr[nf])[i];
                C1[nf][i] = oo;                // reuse C1 as o
                if (nf & 1) { sb += oo; s2b = fmaf(oo, oo, s2b); }
                else        { sa += oo; s2a = fmaf(oo, oo, s2a); }
            }
        }
        float s  = sa + sb;
        float s2 = s2a + s2b;
        s  += __shfl_xor(s,  16, 64);  s  += __shfl_xor(s,  32, 64);
        s2 += __shfl_xor(s2, 16, 64);  s2 += __shfl_xor(s2, 32, 64);
        float mu = s * (1.f/64.f);
        float va = fmaf(s2, 1.f/64.f, -mu*mu);
        float rs = rsqrtf(va + 1e-5f);

        if (n0 + lr < NN) {               // clamped duplicate lanes don't store
            float* pot = po + (size_t)t * ts;
#pragma unroll
            for (int nf = 0; nf < 4; ++nf) {
                f32x4 v;
#pragma unroll
                for (int i = 0; i < 4; ++i)
                    v[i] = fmaf((C1[nf][i] - mu) * rs, bf2f(gpk[nf][i]), bf2f(bpk[nf][i]));
                __builtin_nontemporal_store(v, (f32x4*)(pot + offQ + 16*nf));
            }
        }
    };

    // q rotation period 4, X parity period 2 -> unroll 4 (TCH = 12 = 3x4)
#pragma unroll 1
    for (int tb = 0; tb < TCH; tb += 4) {
        step(tb + 0, qA0,qA1,qA2,qA3,  qD0,qD1,qD2,qD3,  XA, XB);
        step(tb + 1, qB0,qB1,qB2,qB3,  qA0,qA1,qA2,qA3,  XB, XA);
        step(tb + 2, qC0,qC1,qC2,qC3,  qB0,qB1,qB2,qB3,  XA, XB);
        step(tb + 3, qD0,qD1,qD2,qD3,  qC0,qC1,qC2,qC3,  XB, XA);
    }
}

extern "C" void kernel_launch(void* const* d_in, const int* in_sizes, int n_in,
                              void* d_out, int out_size, void* d_ws, size_t ws_size,
                              hipStream_t stream) {
    const float* x     = (const float*)d_in[0];
    // d_in[1] = adj — dead in the reference (overwritten by tiled identity)
    const float* w1    = (const float*)d_in[2];
    const float* b1    = (const float*)d_in[3];
    const float* w2    = (const float*)d_in[4];
    const float* b2    = (const float*)d_in[5];
    const float* gamma = (const float*)d_in[6];
    const float* beta  = (const float*)d_in[7];
    float* out = (float*)d_out;

    dim3 grid(32 * NT * NCH);   // 4032 one-wave blocks (~3.9 waves/SIMD)
    dim3 block(64);
    hipLaunchKernelGGL(stgcn_d3, grid, block, 0, stream,
                       x, w1, b1, w2, b2, gamma, beta, out);
}

// Round 14
// 85.100 us; speedup vs baseline: 1.1502x; 1.0473x over previous
//
#include <hip/hip_runtime.h>
#include <hip/hip_bf16.h>

#define TT 24
#define NN 1000
#define DD 64
#define TCH 6                  // timesteps per wave (4 chunks)
#define NCH (TT / TCH)         // 4
#define NT  63                 // ceil(1000/16) node tiles

typedef short bf16x8 __attribute__((ext_vector_type(8)));
typedef float f32x4  __attribute__((ext_vector_type(4)));

__device__ __forceinline__ short f2bf(float f) {
    __hip_bfloat16 h = __float2bfloat16(f);
    return *reinterpret_cast<short*>(&h);
}

// r14 = r11 with TCH 12 -> 6: 8064 single-wave blocks (~31.5 waves/CU of
// work) to keep all 4 waves/SIMD slots full with fine-grained balancing and
// no tail — r9/r11/r13 all plateaued at ~6.4 resident waves/CU (occupancy
// ~20%) regardless of launched count; effective read BW 2.4-3.9 TB/s of 6.3
// says we're outstanding-request limited. Everything else is r11 verbatim:
// depth-2 prefetch (3 rotating q-sets, unroll 6 = one rotation period),
// k-permuted frags (residual lives in q regs), bias as MFMA C-init, SGPR
// slab bases, nontemporal stores (r12 A/B: plain stores regress replay).
__global__ __launch_bounds__(64, 2)
void stgcn_t6(const float* __restrict__ x,
              const float* __restrict__ w1, const float* __restrict__ b1,
              const float* __restrict__ w2, const float* __restrict__ b2,
              const float* __restrict__ gamma, const float* __restrict__ beta,
              float* __restrict__ out)
{
    const int l   = threadIdx.x & 63;
    const int lr  = l & 15;        // node within tile (C col); frag row
    const int lc  = l >> 4;        // 0..3

    const int w  = __builtin_amdgcn_readfirstlane(blockIdx.x);
    const int nt = w % NT;
    const int tc = (w / NT) % NCH;
    const int b  = w / (NT * NCH);
    const int t0 = tc * TCH;
    const int n0 = nt * 16;

    // ---- single per-lane offset: row lr, word col lc*4 (+16nf immediates)
    const int rowA = min(n0 + lr, NN - 1);
    const int offQ = rowA * DD + lc * 4;

    const size_t ts = (size_t)NN * DD;
    const float* px = x   + (size_t)(b*TT + t0) * ts;   // SGPR slab base
    float*       po = out + (size_t)(b*TT + t0) * ts;

    // ---- issue t0 and t0+1 tile loads ASAP
    f32x4 qA0 = *(const f32x4*)(px + offQ);
    f32x4 qA1 = *(const f32x4*)(px + offQ + 16);
    f32x4 qA2 = *(const f32x4*)(px + offQ + 32);
    f32x4 qA3 = *(const f32x4*)(px + offQ + 48);
    f32x4 qB0 = *(const f32x4*)(px + ts + offQ);
    f32x4 qB1 = *(const f32x4*)(px + ts + offQ + 16);
    f32x4 qB2 = *(const f32x4*)(px + ts + offQ + 32);
    f32x4 qB3 = *(const f32x4*)(px + ts + offQ + 48);
    f32x4 qC0, qC1, qC2, qC3;

    // ---- x_{t0-1} as bf16 frags; zero-pad at t0==0
    bf16x8 XA[2], XB[2];
    if (t0 > 0) {
        const float* pm = px - ts;
        f32x4 m0 = *(const f32x4*)(pm + offQ);
        f32x4 m1 = *(const f32x4*)(pm + offQ + 16);
        f32x4 m2 = *(const f32x4*)(pm + offQ + 32);
        f32x4 m3 = *(const f32x4*)(pm + offQ + 48);
#pragma unroll
        for (int j = 0; j < 4; ++j) {
            XA[0][j]     = f2bf(m0[j]);
            XA[0][4 + j] = f2bf(m1[j]);
            XA[1][j]     = f2bf(m2[j]);
            XA[1][4 + j] = f2bf(m3[j]);
        }
    } else {
        XA[0] = 0; XA[1] = 0;
    }

    // ---- W fragments (A-operand), k-permuted: slot j <- col lc*4+(j&3)+16*(j>>2)+32ks
    bf16x8 W1f[4][2], W2f[4][2];
#pragma unroll
    for (int nf = 0; nf < 4; ++nf) {
#pragma unroll
        for (int ks = 0; ks < 2; ++ks) {
            const float* p1 = &w1[(size_t)(lr + 16*nf) * DD + lc*4 + 32*ks];
            const float* p2 = &w2[(size_t)(lr + 16*nf) * DD + lc*4 + 32*ks];
            f32x4 u0 = *(const f32x4*)p1, u1 = *(const f32x4*)(p1 + 16);
            f32x4 v0 = *(const f32x4*)p2, v1 = *(const f32x4*)(p2 + 16);
#pragma unroll
            for (int j = 0; j < 4; ++j) {
                W1f[nf][ks][j]     = f2bf(0.5f * u0[j]);
                W1f[nf][ks][4 + j] = f2bf(0.5f * u1[j]);
                W2f[nf][ks][j]     = f2bf(0.5f * v0[j]);
                W2f[nf][ks][4 + j] = f2bf(0.5f * v1[j]);
            }
        }
    }
    // ---- epilogue params at d = 16*nf + lc*4 + i
    f32x4 bia1[4], bia2[4], gmm[4], btt[4];
#pragma unroll
    for (int nf = 0; nf < 4; ++nf) {
        const int d0 = 16*nf + lc*4;
        bia1[nf] = *(const f32x4*)&b1[d0];
        bia2[nf] = *(const f32x4*)&b2[d0];
        gmm[nf]  = *(const f32x4*)&gamma[d0];
        btt[nf]  = *(const f32x4*)&beta[d0];
    }

    auto step = [&](int t,
                    f32x4& q0, f32x4& q1, f32x4& q2, f32x4& q3,   // arrived tile (t)
                    f32x4& p0, f32x4& p1, f32x4& p2, f32x4& p3,   // prefetch dest (t+2)
                    bf16x8 (&Xi)[2], bf16x8 (&Xo)[2]) {
        // depth-2 prefetch (clamped at chunk end; dup loads harmless)
        const float* pn = px + (size_t)min(t + 2, TCH - 1) * ts;
        p0 = *(const f32x4*)(pn + offQ);
        p1 = *(const f32x4*)(pn + offQ + 16);
        p2 = *(const f32x4*)(pn + offQ + 32);
        p3 = *(const f32x4*)(pn + offQ + 48);

        // pass 1: prev-frame MFMAs, bias as C-init (register inputs, no waits)
        f32x4 C1[4], C2[4];
#pragma unroll
        for (int nf = 0; nf < 4; ++nf) {
            C1[nf] = __builtin_amdgcn_mfma_f32_16x16x32_bf16(W1f[nf][0], Xi[0], bia1[nf], 0, 0, 0);
            C1[nf] = __builtin_amdgcn_mfma_f32_16x16x32_bf16(W1f[nf][1], Xi[1], C1[nf],   0, 0, 0);
            C2[nf] = __builtin_amdgcn_mfma_f32_16x16x32_bf16(W2f[nf][0], Xi[0], bia2[nf], 0, 0, 0);
            C2[nf] = __builtin_amdgcn_mfma_f32_16x16x32_bf16(W2f[nf][1], Xi[1], C2[nf],   0, 0, 0);
        }

        // arrived tile -> bf16 frags for this step (and next step's prev)
#pragma unroll
        for (int j = 0; j < 4; ++j) {
            Xo[0][j]     = f2bf(q0[j]);
            Xo[0][4 + j] = f2bf(q1[j]);
            Xo[1][j]     = f2bf(q2[j]);
            Xo[1][4 + j] = f2bf(q3[j]);
        }
        // pass 2: current-frame MFMAs
#pragma unroll
        for (int nf = 0; nf < 4; ++nf) {
            C1[nf] = __builtin_amdgcn_mfma_f32_16x16x32_bf16(W1f[nf][0], Xo[0], C1[nf], 0, 0, 0);
            C1[nf] = __builtin_amdgcn_mfma_f32_16x16x32_bf16(W1f[nf][1], Xo[1], C1[nf], 0, 0, 0);
            C2[nf] = __builtin_amdgcn_mfma_f32_16x16x32_bf16(W2f[nf][0], Xo[0], C2[nf], 0, 0, 0);
            C2[nf] = __builtin_amdgcn_mfma_f32_16x16x32_bf16(W2f[nf][1], Xo[1], C2[nf], 0, 0, 0);
        }

        // epilogue: residual IS the q regs (k-permutation payoff)
        float sa = 0.f, sb = 0.f, s2a = 0.f, s2b = 0.f;
        const f32x4* xr[4] = { &q0, &q1, &q2, &q3 };
#pragma unroll
        for (int nf = 0; nf < 4; ++nf) {
#pragma unroll
            for (int i = 0; i < 4; ++i) {
                float h1 = C1[nf][i];          // bias already in C
                float h2 = C2[nf][i];
                float pg = h1 * h2;
                float oo = (pg > 0.f ? pg : 0.f) + h1 + (*xr[nf])[i];
                C1[nf][i] = oo;                // reuse C1 as o
                if (nf & 1) { sb += oo; s2b = fmaf(oo, oo, s2b); }
                else        { sa += oo; s2a = fmaf(oo, oo, s2a); }
            }
        }
        float s  = sa + sb;
        float s2 = s2a + s2b;
        s  += __shfl_xor(s,  16, 64);  s  += __shfl_xor(s,  32, 64);
        s2 += __shfl_xor(s2, 16, 64);  s2 += __shfl_xor(s2, 32, 64);
        float mu = s * (1.f/64.f);
        float va = fmaf(s2, 1.f/64.f, -mu*mu);
        float rs = rsqrtf(va + 1e-5f);

        if (n0 + lr < NN) {               // clamped duplicate lanes don't store
            float* pot = po + (size_t)t * ts;
#pragma unroll
            for (int nf = 0; nf < 4; ++nf) {
                f32x4 v;
#pragma unroll
                for (int i = 0; i < 4; ++i)
                    v[i] = fmaf((C1[nf][i] - mu) * rs, gmm[nf][i], btt[nf][i]);
                __builtin_nontemporal_store(v, (f32x4*)(pot + offQ + 16*nf));
            }
        }
    };

    // q rotation period 3, X parity period 2 -> unroll 6 = TCH
    step(0, qA0,qA1,qA2,qA3,  qC0,qC1,qC2,qC3,  XA, XB);
    step(1, qB0,qB1,qB2,qB3,  qA0,qA1,qA2,qA3,  XB, XA);
    step(2, qC0,qC1,qC2,qC3,  qB0,qB1,qB2,qB3,  XA, XB);
    step(3, qA0,qA1,qA2,qA3,  qC0,qC1,qC2,qC3,  XB, XA);
    step(4, qB0,qB1,qB2,qB3,  qA0,qA1,qA2,qA3,  XA, XB);
    step(5, qC0,qC1,qC2,qC3,  qB0,qB1,qB2,qB3,  XB, XA);
}

extern "C" void kernel_launch(void* const* d_in, const int* in_sizes, int n_in,
                              void* d_out, int out_size, void* d_ws, size_t ws_size,
                              hipStream_t stream) {
    const float* x     = (const float*)d_in[0];
    // d_in[1] = adj — dead in the reference (overwritten by tiled identity)
    const float* w1    = (const float*)d_in[2];
    const float* b1    = (const float*)d_in[3];
    const float* w2    = (const float*)d_in[4];
    const float* b2    = (const float*)d_in[5];
    const float* gamma = (const float*)d_in[6];
    const float* beta  = (const float*)d_in[7];
    float* out = (float*)d_out;

    dim3 grid(32 * NT * NCH);   // 8064 one-wave blocks
    dim3 block(64);
    hipLaunchKernelGGL(stgcn_t6, grid, block, 0, stream,
                       x, w1, b1, w2, b2, gamma, beta, out);
}

// Round 15
// 71.706 us; speedup vs baseline: 1.3651x; 1.1868x over previous
//
#include <hip/hip_runtime.h>
#include <hip/hip_bf16.h>

#define TT 24
#define NN 1000
#define DD 64
#define TCH 12                 // timesteps per wave (2 chunks)
#define NCH (TT / TCH)         // 2
#define NT  63                 // ceil(1000/16) node tiles

typedef short bf16x8 __attribute__((ext_vector_type(8)));
typedef float f32x4  __attribute__((ext_vector_type(4)));

__device__ __forceinline__ short f2bf(float f) {
    __hip_bfloat16 h = __float2bfloat16(f);
    return *reinterpret_cast<short*>(&h);
}

// r15 = r11 (best, 79.9us) with ONE change: the store path. r11's nt stores
// wrote 64B per 128B line per instruction (16 scattered rows) -> partial-line
// HBM writes, WRITE_SIZE +10-18%, ~2.6TB/s write traffic at half burst
// efficiency. Here each step stages its 16 y-values/lane through a 4KB
// swizzled LDS tile (4 ds_write_b128 + 4 ds_read_b128, single wave = no
// barrier) and the 4 nt stores become 1024B-contiguous per instruction
// (8 full lines each). Everything else r11 verbatim: depth-2 prefetch with 3
// rotating q-sets, k-permuted frags (residual lives in q regs), bias as MFMA
// C-init, SGPR slab bases, nontemporal stores (r12: plain stores regress
// replay via L2 writeback contention).
__global__ __launch_bounds__(64, 2)
void stgcn_ts(const float* __restrict__ x,
              const float* __restrict__ w1, const float* __restrict__ b1,
              const float* __restrict__ w2, const float* __restrict__ b2,
              const float* __restrict__ gamma, const float* __restrict__ beta,
              float* __restrict__ out)
{
    const int l   = threadIdx.x & 63;
    const int lr  = l & 15;        // node within tile (C col); frag row
    const int lc  = l >> 4;        // 0..3

    const int w  = __builtin_amdgcn_readfirstlane(blockIdx.x);
    const int nt = w % NT;
    const int tc = (w / NT) % NCH;
    const int b  = w / (NT * NCH);
    const int t0 = tc * TCH;
    const int n0 = nt * 16;

    __shared__ float ls[16 * DD];   // 4KB transpose-staging tile (swizzled)

    // ---- single per-lane offset: row lr, word col lc*4 (+16nf immediates)
    const int rowA = min(n0 + lr, NN - 1);
    const int offQ = rowA * DD + lc * 4;

    const size_t ts = (size_t)NN * DD;
    const float* px = x   + (size_t)(b*TT + t0) * ts;   // SGPR slab base
    float*       po = out + (size_t)(b*TT + t0) * ts;

    // ---- issue t0 and t0+1 tile loads ASAP
    f32x4 qA0 = *(const f32x4*)(px + offQ);
    f32x4 qA1 = *(const f32x4*)(px + offQ + 16);
    f32x4 qA2 = *(const f32x4*)(px + offQ + 32);
    f32x4 qA3 = *(const f32x4*)(px + offQ + 48);
    f32x4 qB0 = *(const f32x4*)(px + ts + offQ);
    f32x4 qB1 = *(const f32x4*)(px + ts + offQ + 16);
    f32x4 qB2 = *(const f32x4*)(px + ts + offQ + 32);
    f32x4 qB3 = *(const f32x4*)(px + ts + offQ + 48);
    f32x4 qC0, qC1, qC2, qC3;

    // ---- x_{t0-1} as bf16 frags; zero-pad at t0==0
    bf16x8 XA[2], XB[2];
    if (t0 > 0) {
        const float* pm = px - ts;
        f32x4 m0 = *(const f32x4*)(pm + offQ);
        f32x4 m1 = *(const f32x4*)(pm + offQ + 16);
        f32x4 m2 = *(const f32x4*)(pm + offQ + 32);
        f32x4 m3 = *(const f32x4*)(pm + offQ + 48);
#pragma unroll
        for (int j = 0; j < 4; ++j) {
            XA[0][j]     = f2bf(m0[j]);
            XA[0][4 + j] = f2bf(m1[j]);
            XA[1][j]     = f2bf(m2[j]);
            XA[1][4 + j] = f2bf(m3[j]);
        }
    } else {
        XA[0] = 0; XA[1] = 0;
    }

    // ---- W fragments (A-operand), k-permuted: slot j <- col lc*4+(j&3)+16*(j>>2)+32ks
    bf16x8 W1f[4][2], W2f[4][2];
#pragma unroll
    for (int nf = 0; nf < 4; ++nf) {
#pragma unroll
        for (int ks = 0; ks < 2; ++ks) {
            const float* p1 = &w1[(size_t)(lr + 16*nf) * DD + lc*4 + 32*ks];
            const float* p2 = &w2[(size_t)(lr + 16*nf) * DD + lc*4 + 32*ks];
            f32x4 u0 = *(const f32x4*)p1, u1 = *(const f32x4*)(p1 + 16);
            f32x4 v0 = *(const f32x4*)p2, v1 = *(const f32x4*)(p2 + 16);
#pragma unroll
            for (int j = 0; j < 4; ++j) {
                W1f[nf][ks][j]     = f2bf(0.5f * u0[j]);
                W1f[nf][ks][4 + j] = f2bf(0.5f * u1[j]);
                W2f[nf][ks][j]     = f2bf(0.5f * v0[j]);
                W2f[nf][ks][4 + j] = f2bf(0.5f * v1[j]);
            }
        }
    }
    // ---- epilogue params at d = 16*nf + lc*4 + i
    f32x4 bia1[4], bia2[4], gmm[4], btt[4];
#pragma unroll
    for (int nf = 0; nf < 4; ++nf) {
        const int d0 = 16*nf + lc*4;
        bia1[nf] = *(const f32x4*)&b1[d0];
        bia2[nf] = *(const f32x4*)&b2[d0];
        gmm[nf]  = *(const f32x4*)&gamma[d0];
        btt[nf]  = *(const f32x4*)&beta[d0];
    }

    auto step = [&](int t,
                    f32x4& q0, f32x4& q1, f32x4& q2, f32x4& q3,   // arrived tile (t)
                    f32x4& p0, f32x4& p1, f32x4& p2, f32x4& p3,   // prefetch dest (t+2)
                    bf16x8 (&Xi)[2], bf16x8 (&Xo)[2]) {
        // depth-2 prefetch (clamped at chunk end; dup loads harmless)
        const float* pn = px + (size_t)min(t + 2, TCH - 1) * ts;
        p0 = *(const f32x4*)(pn + offQ);
        p1 = *(const f32x4*)(pn + offQ + 16);
        p2 = *(const f32x4*)(pn + offQ + 32);
        p3 = *(const f32x4*)(pn + offQ + 48);

        // pass 1: prev-frame MFMAs, bias as C-init (register inputs, no waits)
        f32x4 C1[4], C2[4];
#pragma unroll
        for (int nf = 0; nf < 4; ++nf) {
            C1[nf] = __builtin_amdgcn_mfma_f32_16x16x32_bf16(W1f[nf][0], Xi[0], bia1[nf], 0, 0, 0);
            C1[nf] = __builtin_amdgcn_mfma_f32_16x16x32_bf16(W1f[nf][1], Xi[1], C1[nf],   0, 0, 0);
            C2[nf] = __builtin_amdgcn_mfma_f32_16x16x32_bf16(W2f[nf][0], Xi[0], bia2[nf], 0, 0, 0);
            C2[nf] = __builtin_amdgcn_mfma_f32_16x16x32_bf16(W2f[nf][1], Xi[1], C2[nf],   0, 0, 0);
        }

        // arrived tile -> bf16 frags for this step (and next step's prev)
#pragma unroll
        for (int j = 0; j < 4; ++j) {
            Xo[0][j]     = f2bf(q0[j]);
            Xo[0][4 + j] = f2bf(q1[j]);
            Xo[1][j]     = f2bf(q2[j]);
            Xo[1][4 + j] = f2bf(q3[j]);
        }
        // pass 2: current-frame MFMAs
#pragma unroll
        for (int nf = 0; nf < 4; ++nf) {
            C1[nf] = __builtin_amdgcn_mfma_f32_16x16x32_bf16(W1f[nf][0], Xo[0], C1[nf], 0, 0, 0);
            C1[nf] = __builtin_amdgcn_mfma_f32_16x16x32_bf16(W1f[nf][1], Xo[1], C1[nf], 0, 0, 0);
            C2[nf] = __builtin_amdgcn_mfma_f32_16x16x32_bf16(W2f[nf][0], Xo[0], C2[nf], 0, 0, 0);
            C2[nf] = __builtin_amdgcn_mfma_f32_16x16x32_bf16(W2f[nf][1], Xo[1], C2[nf], 0, 0, 0);
        }

        // epilogue: residual IS the q regs (k-permutation payoff)
        float sa = 0.f, sb = 0.f, s2a = 0.f, s2b = 0.f;
        const f32x4* xr[4] = { &q0, &q1, &q2, &q3 };
#pragma unroll
        for (int nf = 0; nf < 4; ++nf) {
#pragma unroll
            for (int i = 0; i < 4; ++i) {
                float h1 = C1[nf][i];          // bias already in C
                float h2 = C2[nf][i];
                float pg = h1 * h2;
                float oo = (pg > 0.f ? pg : 0.f) + h1 + (*xr[nf])[i];
                C1[nf][i] = oo;                // reuse C1 as o
                if (nf & 1) { sb += oo; s2b = fmaf(oo, oo, s2b); }
                else        { sa += oo; s2a = fmaf(oo, oo, s2a); }
            }
        }
        float s  = sa + sb;
        float s2 = s2a + s2b;
        s  += __shfl_xor(s,  16, 64);  s  += __shfl_xor(s,  32, 64);
        s2 += __shfl_xor(s2, 16, 64);  s2 += __shfl_xor(s2, 32, 64);
        float mu = s * (1.f/64.f);
        float va = fmaf(s2, 1.f/64.f, -mu*mu);
        float rs = rsqrtf(va + 1e-5f);

        // ---- y -> LDS (swizzled), read transposed, nt store FULL LINES ----
        float* pot = po + (size_t)t * ts;
#pragma unroll
        for (int nf = 0; nf < 4; ++nf) {
            f32x4 v;
#pragma unroll
            for (int i = 0; i < 4; ++i)
                v[i] = fmaf((C1[nf][i] - mu) * rs, gmm[nf][i], btt[nf][i]);
            const int wc = 16*nf + lc*4;
            *(f32x4*)&ls[lr*DD + (wc ^ ((lr & 7) << 2))] = v;
        }
#pragma unroll
        for (int s4 = 0; s4 < 4; ++s4) {
            const int rr = 4*s4 + (l >> 4);        // tile row this lane stores
            const int wc = (l & 15) * 4;           // word col
            f32x4 v = *(const f32x4*)&ls[rr*DD + (wc ^ ((rr & 7) << 2))];
            if (n0 + rr < NN)                      // wave-uniform per s4
                __builtin_nontemporal_store(v, (f32x4*)(pot + (size_t)(n0 + rr)*DD + wc));
        }
    };

    // q rotation period 3, X parity period 2 -> unroll 6 (TCH = 12 = 2x6)
#pragma unroll 1
    for (int tb = 0; tb < TCH; tb += 6) {
        step(tb + 0, qA0,qA1,qA2,qA3,  qC0,qC1,qC2,qC3,  XA, XB);
        step(tb + 1, qB0,qB1,qB2,qB3,  qA0,qA1,qA2,qA3,  XB, XA);
        step(tb + 2, qC0,qC1,qC2,qC3,  qB0,qB1,qB2,qB3,  XA, XB);
        step(tb + 3, qA0,qA1,qA2,qA3,  qC0,qC1,qC2,qC3,  XB, XA);
        step(tb + 4, qB0,qB1,qB2,qB3,  qA0,qA1,qA2,qA3,  XA, XB);
        step(tb + 5, qC0,qC1,qC2,qC3,  qB0,qB1,qB2,qB3,  XB, XA);
    }
}

extern "C" void kernel_launch(void* const* d_in, const int* in_sizes, int n_in,
                              void* d_out, int out_size, void* d_ws, size_t ws_size,
                              hipStream_t stream) {
    const float* x     = (const float*)d_in[0];
    // d_in[1] = adj — dead in the reference (overwritten by tiled identity)
    const float* w1    = (const float*)d_in[2];
    const float* b1    = (const float*)d_in[3];
    const float* w2    = (const float*)d_in[4];
    const float* b2    = (const float*)d_in[5];
    const float* gamma = (const float*)d_in[6];
    const float* beta  = (const float*)d_in[7];
    float* out = (float*)d_out;

    dim3 grid(32 * NT * NCH);   // 4032 one-wave blocks
    dim3 block(64);
    hipLaunchKernelGGL(stgcn_ts, grid, block, 0, stream,
                       x, w1, b1, w2, b2, gamma, beta, out);
}